// Round 1
// baseline (3478.511 us; speedup 1.0000x reference)
//
#include <hip/hip_runtime.h>

// HeteroGNN fused implementation.
// Algebraic restructure:
//   m = [x_src | x_dst] @ Wm + bm ; agg = segsum(m, dst)
//   => agg = segsum(x_src,dst) @ Wm_top + deg .* (x_dst @ Wm_bot + bm)
//   new = [agg | x] @ Wu + bu
//   => new = S @ (Wm_top@Wu_top) + deg.*(x @ (Wm_bot@Wu_top)) + x @ Wu_bot
//            + deg.*(bm@Wu_top) + bu
// i.e. one GEMM per relation per layer: [M,384] @ [384,128] with virtual
// input rows [S_row | deg*x_row | x_row].

#define H 128
#define NN 50000
#define NL 50000
#define NE 400000
#define NG 64

// ---------------- weight fusion ----------------
// Wstack[combo][384][128]; combo c: l=c>>1, rel=c&1 (0 = nl->link update, 1 = ln->node update)
__global__ void precompute_w(const float* __restrict__ Wm_nl, const float* __restrict__ bm_nl,
                             const float* __restrict__ Wu_nl,
                             const float* __restrict__ Wm_ln, const float* __restrict__ bm_ln,
                             const float* __restrict__ Wu_ln,
                             float* __restrict__ Wstack, float* __restrict__ bmp) {
    int idx = blockIdx.x * blockDim.x + threadIdx.x;
    const int per = 384 * H + H;
    int c = idx / per, r = idx % per;
    if (c >= 4) return;
    int l = c >> 1, rel = c & 1;
    const float* Wm = (rel ? Wm_ln : Wm_nl) + l * 256 * H;
    const float* Wu = (rel ? Wu_ln : Wu_nl) + l * 256 * H;
    const float* bm = (rel ? bm_ln : bm_nl) + l * H;
    float* Ws = Wstack + c * 384 * H;
    if (r < 384 * H) {
        int t = r / H, j = r % H;
        if (t < 256) {
            // rows 0..127: Wm_top @ Wu_top ; rows 128..255: Wm_bot @ Wu_top
            float acc = 0.f;
            for (int k = 0; k < H; ++k) acc += Wm[t * H + k] * Wu[k * H + j];
            Ws[t * H + j] = acc;
        } else {
            // rows 256..383: Wu_bot (copy)
            Ws[t * H + j] = Wu[(t - 128) * H + j];
        }
    } else {
        int j = r - 384 * H;
        float acc = 0.f;
        for (int k = 0; k < H; ++k) acc += bm[k] * Wu[k * H + j];
        bmp[c * H + j] = acc;
    }
}

// ---------------- feature padding ----------------
__global__ void init_x(const float* __restrict__ xn_raw, const float* __restrict__ xl_raw,
                       float* __restrict__ xn, float* __restrict__ xl) {
    int idx = blockIdx.x * blockDim.x + threadIdx.x;   // 2*NN*H threads
    int which = idx / (NN * H);
    int rem = idx - which * (NN * H);
    int r = rem / H, c = rem - r * H;
    const float* src = which ? xl_raw : xn_raw;
    float v = (c < 8) ? src[r * 8 + c] : 0.f;
    (which ? xl : xn)[rem] = v;
}

// ---------------- degree ----------------
__global__ void compute_deg(const int* __restrict__ nl, const int* __restrict__ ln,
                            float* __restrict__ deg_l, float* __restrict__ deg_n) {
    int e = blockIdx.x * blockDim.x + threadIdx.x;
    if (e < NE) {
        atomicAdd(&deg_l[nl[NE + e]], 1.f);
        atomicAdd(&deg_n[ln[NE + e]], 1.f);
    }
}

// ---------------- scatter-sum of raw features: S[dst] += X[src] ----------------
__global__ void scatter_sum(const int* __restrict__ edge, const float* __restrict__ X,
                            float* __restrict__ S) {
    long t = (long)blockIdx.x * blockDim.x + threadIdx.x;
    int e = (int)(t >> 5), q = (int)(t & 31);
    if (e >= NE) return;
    int src = edge[e];
    int dst = edge[NE + e];
    float4 v = *(const float4*)(X + (long)src * H + q * 4);
    float* p = S + (long)dst * H + q * 4;
    atomicAdd(p + 0, v.x);
    atomicAdd(p + 1, v.y);
    atomicAdd(p + 2, v.z);
    atomicAdd(p + 3, v.w);
}

// ---------------- fused update GEMM ----------------
// Out[M,128] = relu( [S | deg.*X | X] @ Ws(384x128) + deg.*bmp + bu ), in-place Out==X safe
#define BM 64
#define BK 32
__launch_bounds__(256)
__global__ void gemm_update(const float* __restrict__ S, const float* __restrict__ X,
                            const float* __restrict__ deg, const float* __restrict__ Ws,
                            const float* __restrict__ bmp, const float* __restrict__ bu,
                            float* __restrict__ Out, int M) {
    __shared__ float At[BK][BM + 4];   // [k][m], padded
    __shared__ float Bt[BK][H];
    int tid = threadIdx.x;
    int rowg = tid >> 4;     // 0..15 -> 4 rows each
    int colg = tid & 15;     // 0..15 -> 8 cols each
    int m0 = blockIdx.x * BM;
    float acc[4][8] = {};

    for (int k0 = 0; k0 < 384; k0 += BK) {
        // stage A: 64 rows x 32 k
#pragma unroll
        for (int p = 0; p < 2; ++p) {
            int idx = tid + p * 256;
            int r = idx >> 3, kg = idx & 7;
            int row = m0 + r;
            int k = k0 + kg * 4;
            float4 v = make_float4(0.f, 0.f, 0.f, 0.f);
            if (row < M) {
                if (k < 128) {
                    v = *(const float4*)(S + (long)row * H + k);
                } else if (k < 256) {
                    v = *(const float4*)(X + (long)row * H + (k - 128));
                    float d = deg[row];
                    v.x *= d; v.y *= d; v.z *= d; v.w *= d;
                } else {
                    v = *(const float4*)(X + (long)row * H + (k - 256));
                }
            }
            At[kg * 4 + 0][r] = v.x;
            At[kg * 4 + 1][r] = v.y;
            At[kg * 4 + 2][r] = v.z;
            At[kg * 4 + 3][r] = v.w;
        }
        // stage B: 32 x 128 weights
#pragma unroll
        for (int p = 0; p < 4; ++p) {
            int idx = tid + p * 256;
            int kk = idx >> 5, c4 = idx & 31;
            *(float4*)(&Bt[kk][c4 * 4]) = *(const float4*)(Ws + (long)(k0 + kk) * H + c4 * 4);
        }
        __syncthreads();
#pragma unroll
        for (int kk = 0; kk < BK; ++kk) {
            float a[4], b[8];
            *(float4*)a = *(const float4*)(&At[kk][rowg * 4]);
            *(float4*)(b) = *(const float4*)(&Bt[kk][colg * 8]);
            *(float4*)(b + 4) = *(const float4*)(&Bt[kk][colg * 8 + 4]);
#pragma unroll
            for (int i = 0; i < 4; ++i)
#pragma unroll
                for (int j = 0; j < 8; ++j)
                    acc[i][j] += a[i] * b[j];
        }
        __syncthreads();
    }

    int colbase = colg * 8;
    float bmv[8], buv[8];
#pragma unroll
    for (int j = 0; j < 8; ++j) { bmv[j] = bmp[colbase + j]; buv[j] = bu[colbase + j]; }
#pragma unroll
    for (int i = 0; i < 4; ++i) {
        int row = m0 + rowg * 4 + i;
        if (row < M) {
            float d = deg[row];
            float o[8];
#pragma unroll
            for (int j = 0; j < 8; ++j) {
                float v = acc[i][j] + d * bmv[j] + buv[j];
                o[j] = v > 0.f ? v : 0.f;
            }
            *(float4*)(Out + (long)row * H + colbase) = *(float4*)o;
            *(float4*)(Out + (long)row * H + colbase + 4) = *(float4*)(o + 4);
        }
    }
}

// ---------------- global mean pool ----------------
__global__ void pool_sum(const float* __restrict__ xl, const int* __restrict__ batch,
                         float* __restrict__ sums, float* __restrict__ cnt) {
    int row = blockIdx.x;
    int col = threadIdx.x;
    int g = batch[row];
    atomicAdd(&sums[g * H + col], xl[(long)row * H + col]);
    if (col == 0) atomicAdd(&cnt[g], 1.f);
}

__global__ void pool_final(const float* __restrict__ sums, const float* __restrict__ cnt,
                           float* __restrict__ out) {
    int idx = blockIdx.x * blockDim.x + threadIdx.x;   // NG*H
    int g = idx / H;
    out[idx] = sums[idx] / fmaxf(cnt[g], 1.f);
}

extern "C" void kernel_launch(void* const* d_in, const int* in_sizes, int n_in,
                              void* d_out, int out_size, void* d_ws, size_t ws_size,
                              hipStream_t stream) {
    const float* x_node = (const float*)d_in[0];
    const float* x_link = (const float*)d_in[1];
    const float* Wm_nl  = (const float*)d_in[2];
    const float* bm_nl  = (const float*)d_in[3];
    const float* Wu_nl  = (const float*)d_in[4];
    const float* bu_nl  = (const float*)d_in[5];
    const float* Wm_ln  = (const float*)d_in[6];
    const float* bm_ln  = (const float*)d_in[7];
    const float* Wu_ln  = (const float*)d_in[8];
    const float* bu_ln  = (const float*)d_in[9];
    const int* nl_edge  = (const int*)d_in[10];
    const int* ln_edge  = (const int*)d_in[11];
    const int* batch_link = (const int*)d_in[12];

    // workspace layout (fp32): ~103.5 MB total
    float* ws    = (float*)d_ws;
    float* xn    = ws;  ws += (long)NN * H;
    float* xl    = ws;  ws += (long)NL * H;
    float* Sl    = ws;  ws += (long)NL * H;
    float* Sn    = ws;  ws += (long)NN * H;
    float* deg_l = ws;  ws += NL;
    float* deg_n = ws;  ws += NN;
    float* Wstack= ws;  ws += 4L * 384 * H;
    float* bmp   = ws;  ws += 4 * H;
    float* sums  = ws;  ws += NG * H;
    float* cnt   = ws;  ws += NG;

    // zero: degrees + pool accumulators (deg_l/deg_n contiguous; sums/cnt contiguous)
    hipMemsetAsync(deg_l, 0, (size_t)(NL + NN) * sizeof(float), stream);
    hipMemsetAsync(sums, 0, (size_t)(NG * H + NG) * sizeof(float), stream);

    precompute_w<<<(4 * (384 * H + H) + 255) / 256, 256, 0, stream>>>(
        Wm_nl, bm_nl, Wu_nl, Wm_ln, bm_ln, Wu_ln, Wstack, bmp);
    init_x<<<(2 * NN * H) / 256, 256, 0, stream>>>(x_node, x_link, xn, xl);
    compute_deg<<<(NE + 255) / 256, 256, 0, stream>>>(nl_edge, ln_edge, deg_l, deg_n);

    const float* bu_nl_l[2] = { bu_nl, bu_nl + H };
    const float* bu_ln_l[2] = { bu_ln, bu_ln + H };

    for (int l = 0; l < 2; ++l) {
        // zero both scatter buffers (contiguous)
        hipMemsetAsync(Sl, 0, (size_t)(NL + NN) * H * sizeof(float), stream);
        // aggregate raw features (both relations read OLD xn/xl)
        scatter_sum<<<(NE * 32) / 256, 256, 0, stream>>>(nl_edge, xn, Sl);
        scatter_sum<<<(NE * 32) / 256, 256, 0, stream>>>(ln_edge, xl, Sn);
        // fused message+update GEMMs (in-place row-wise updates)
        gemm_update<<<(NL + BM - 1) / BM, 256, 0, stream>>>(
            Sl, xl, deg_l, Wstack + (size_t)(2 * l) * 384 * H, bmp + (2 * l) * H,
            bu_nl_l[l], xl, NL);
        gemm_update<<<(NN + BM - 1) / BM, 256, 0, stream>>>(
            Sn, xn, deg_n, Wstack + (size_t)(2 * l + 1) * 384 * H, bmp + (2 * l + 1) * H,
            bu_ln_l[l], xn, NN);
    }

    pool_sum<<<NL, H, 0, stream>>>(xl, batch_link, sums, cnt);
    pool_final<<<(NG * H) / 256, 256, 0, stream>>>(sums, cnt, (float*)d_out);
}

// Round 2
// 770.483 us; speedup vs baseline: 4.5147x; 4.5147x over previous
//
#include <hip/hip_runtime.h>

// HeteroGNN fused implementation, round 2.
// Algebraic restructure (unchanged from round 1):
//   new = relu( S @ (Wm_top@Wu_top) + deg.*(x @ (Wm_bot@Wu_top)) + x @ Wu_bot
//               + deg.*(bm@Wu_top) + bu )
// Round-2 change: scatter-sum via fp32 atomics (800MB write-through per
// dispatch, 674us x4) replaced by CSR build (once) + wave-per-row gather.

#define H 128
#define NN 50000
#define NL 50000
#define NE 400000
#define NG 64

// ---------------- weight fusion ----------------
__global__ void precompute_w(const float* __restrict__ Wm_nl, const float* __restrict__ bm_nl,
                             const float* __restrict__ Wu_nl,
                             const float* __restrict__ Wm_ln, const float* __restrict__ bm_ln,
                             const float* __restrict__ Wu_ln,
                             float* __restrict__ Wstack, float* __restrict__ bmp) {
    int idx = blockIdx.x * blockDim.x + threadIdx.x;
    const int per = 384 * H + H;
    int c = idx / per, r = idx % per;
    if (c >= 4) return;
    int l = c >> 1, rel = c & 1;
    const float* Wm = (rel ? Wm_ln : Wm_nl) + l * 256 * H;
    const float* Wu = (rel ? Wu_ln : Wu_nl) + l * 256 * H;
    const float* bm = (rel ? bm_ln : bm_nl) + l * H;
    float* Ws = Wstack + c * 384 * H;
    if (r < 384 * H) {
        int t = r / H, j = r % H;
        if (t < 256) {
            float acc = 0.f;
            for (int k = 0; k < H; ++k) acc += Wm[t * H + k] * Wu[k * H + j];
            Ws[t * H + j] = acc;
        } else {
            Ws[t * H + j] = Wu[(t - 128) * H + j];
        }
    } else {
        int j = r - 384 * H;
        float acc = 0.f;
        for (int k = 0; k < H; ++k) acc += bm[k] * Wu[k * H + j];
        bmp[c * H + j] = acc;
    }
}

// ---------------- feature padding ----------------
__global__ void init_x(const float* __restrict__ xn_raw, const float* __restrict__ xl_raw,
                       float* __restrict__ xn, float* __restrict__ xl) {
    int idx = blockIdx.x * blockDim.x + threadIdx.x;   // 2*NN*H threads
    int which = idx / (NN * H);
    int rem = idx - which * (NN * H);
    int r = rem / H, c = rem - r * H;
    const float* src = which ? xl_raw : xn_raw;
    float v = (c < 8) ? src[r * 8 + c] : 0.f;
    (which ? xl : xn)[rem] = v;
}

// ---------------- degree (int) ----------------
__global__ void compute_deg(const int* __restrict__ nl, const int* __restrict__ ln,
                            int* __restrict__ dl, int* __restrict__ dn) {
    int e = blockIdx.x * blockDim.x + threadIdx.x;
    if (e < NE) {
        atomicAdd(&dl[nl[NE + e]], 1);
        atomicAdd(&dn[ln[NE + e]], 1);
    }
}

// ---------------- offsets via single-block scan (blockIdx.x selects array) ----------------
__global__ void build_offsets(const int* __restrict__ degL, const int* __restrict__ degN,
                              int* __restrict__ offL, int* __restrict__ offN,
                              int* __restrict__ curL, int* __restrict__ curN,
                              float* __restrict__ fdegL, float* __restrict__ fdegN) {
    const int M = NL;  // == NN
    const int* deg = blockIdx.x ? degN : degL;
    int* off = blockIdx.x ? offN : offL;
    int* cur = blockIdx.x ? curN : curL;
    float* fdeg = blockIdx.x ? fdegN : fdegL;
    __shared__ int part[256];
    int tid = threadIdx.x;
    const int chunk = (M + 255) / 256;
    int start = tid * chunk;
    int s = 0;
    for (int i = 0; i < chunk; ++i) {
        int idx = start + i;
        if (idx < M) s += deg[idx];
    }
    part[tid] = s;
    __syncthreads();
    for (int d = 1; d < 256; d <<= 1) {
        int v = (tid >= d) ? part[tid - d] : 0;
        __syncthreads();
        if (tid >= d) part[tid] += v;
        __syncthreads();
    }
    int run = (tid ? part[tid - 1] : 0);
    for (int i = 0; i < chunk; ++i) {
        int idx = start + i;
        if (idx < M) {
            off[idx] = run;
            cur[idx] = run;
            fdeg[idx] = (float)deg[idx];
            run += deg[idx];
        }
    }
    if (tid == 255) off[M] = run;
}

// ---------------- CSR fill ----------------
__global__ void fill_csr(const int* __restrict__ nl, const int* __restrict__ ln,
                         int* __restrict__ curL, int* __restrict__ curN,
                         int* __restrict__ adjL, int* __restrict__ adjN) {
    int e = blockIdx.x * blockDim.x + threadIdx.x;
    if (e >= NE) return;
    {
        int src = nl[e], dst = nl[NE + e];
        int p = atomicAdd(&curL[dst], 1);
        adjL[p] = src;
    }
    {
        int src = ln[e], dst = ln[NE + e];
        int p = atomicAdd(&curN[dst], 1);
        adjN[p] = src;
    }
}

// ---------------- gather-sum: S[row] = sum_{i in adj[off[row]..off[row+1])} X[i] ----------------
__launch_bounds__(256)
__global__ void gather_sum(const int* __restrict__ off, const int* __restrict__ adj,
                           const float* __restrict__ X, float* __restrict__ S, int M) {
    int row = blockIdx.x * 4 + (threadIdx.x >> 6);
    int lane = threadIdx.x & 63;
    if (row >= M) return;
    int beg = off[row], end = off[row + 1];
    float2 acc = make_float2(0.f, 0.f);
    int i = beg;
    for (; i + 1 < end; i += 2) {
        int s0 = adj[i], s1 = adj[i + 1];
        float2 a = *(const float2*)(X + (long)s0 * H + lane * 2);
        float2 b = *(const float2*)(X + (long)s1 * H + lane * 2);
        acc.x += a.x + b.x;
        acc.y += a.y + b.y;
    }
    if (i < end) {
        int s0 = adj[i];
        float2 a = *(const float2*)(X + (long)s0 * H + lane * 2);
        acc.x += a.x;
        acc.y += a.y;
    }
    *(float2*)(S + (long)row * H + lane * 2) = acc;
}

// ---------------- fused update GEMM ----------------
// Out[M,128] = relu( [S | deg.*X | X] @ Ws(384x128) + deg.*bmp + bu ), in-place Out==X safe
#define BM 64
#define BK 32
__launch_bounds__(256)
__global__ void gemm_update(const float* __restrict__ S, const float* __restrict__ X,
                            const float* __restrict__ deg, const float* __restrict__ Ws,
                            const float* __restrict__ bmp, const float* __restrict__ bu,
                            float* __restrict__ Out, int M) {
    __shared__ float At[BK][BM + 4];   // [k][m], padded
    __shared__ float Bt[BK][H];
    int tid = threadIdx.x;
    int rowg = tid >> 4;     // 0..15 -> 4 rows each
    int colg = tid & 15;     // 0..15 -> 8 cols each
    int m0 = blockIdx.x * BM;
    float acc[4][8] = {};

    for (int k0 = 0; k0 < 384; k0 += BK) {
#pragma unroll
        for (int p = 0; p < 2; ++p) {
            int idx = tid + p * 256;
            int r = idx >> 3, kg = idx & 7;
            int row = m0 + r;
            int k = k0 + kg * 4;
            float4 v = make_float4(0.f, 0.f, 0.f, 0.f);
            if (row < M) {
                if (k < 128) {
                    v = *(const float4*)(S + (long)row * H + k);
                } else if (k < 256) {
                    v = *(const float4*)(X + (long)row * H + (k - 128));
                    float d = deg[row];
                    v.x *= d; v.y *= d; v.z *= d; v.w *= d;
                } else {
                    v = *(const float4*)(X + (long)row * H + (k - 256));
                }
            }
            At[kg * 4 + 0][r] = v.x;
            At[kg * 4 + 1][r] = v.y;
            At[kg * 4 + 2][r] = v.z;
            At[kg * 4 + 3][r] = v.w;
        }
#pragma unroll
        for (int p = 0; p < 4; ++p) {
            int idx = tid + p * 256;
            int kk = idx >> 5, c4 = idx & 31;
            *(float4*)(&Bt[kk][c4 * 4]) = *(const float4*)(Ws + (long)(k0 + kk) * H + c4 * 4);
        }
        __syncthreads();
#pragma unroll
        for (int kk = 0; kk < BK; ++kk) {
            float a[4], b[8];
            *(float4*)a = *(const float4*)(&At[kk][rowg * 4]);
            *(float4*)(b) = *(const float4*)(&Bt[kk][colg * 8]);
            *(float4*)(b + 4) = *(const float4*)(&Bt[kk][colg * 8 + 4]);
#pragma unroll
            for (int i = 0; i < 4; ++i)
#pragma unroll
                for (int j = 0; j < 8; ++j)
                    acc[i][j] += a[i] * b[j];
        }
        __syncthreads();
    }

    int colbase = colg * 8;
    float bmv[8], buv[8];
#pragma unroll
    for (int j = 0; j < 8; ++j) { bmv[j] = bmp[colbase + j]; buv[j] = bu[colbase + j]; }
#pragma unroll
    for (int i = 0; i < 4; ++i) {
        int row = m0 + rowg * 4 + i;
        if (row < M) {
            float d = deg[row];
            float o[8];
#pragma unroll
            for (int j = 0; j < 8; ++j) {
                float v = acc[i][j] + d * bmv[j] + buv[j];
                o[j] = v > 0.f ? v : 0.f;
            }
            *(float4*)(Out + (long)row * H + colbase) = *(float4*)o;
            *(float4*)(Out + (long)row * H + colbase + 4) = *(float4*)(o + 4);
        }
    }
}

// ---------------- global mean pool (sorted batch, low-contention) ----------------
#define PR 256   // rows per block
__global__ void pool_sum(const float* __restrict__ xl, const int* __restrict__ batch,
                         float* __restrict__ sums) {
    int base = blockIdx.x * PR;
    int col = threadIdx.x & 127;
    int half = threadIdx.x >> 7;   // 0/1
    int rows = min(PR, NL - base);
    float acc = 0.f;
    int cur = -1;
    for (int r = half; r < rows; r += 2) {
        int row = base + r;
        int g = batch[row];
        if (g != cur) {
            if (cur >= 0) atomicAdd(&sums[cur * H + col], acc);
            acc = 0.f;
            cur = g;
        }
        acc += xl[(long)row * H + col];
    }
    if (cur >= 0) atomicAdd(&sums[cur * H + col], acc);
}

__global__ void pool_counts(const int* __restrict__ batch, float* __restrict__ cnt) {
    int g = threadIdx.x;   // 64 threads
    if (g >= NG) return;
    int lo = 0, hi = NL;
    while (lo < hi) { int mid = (lo + hi) >> 1; if (batch[mid] < g) lo = mid + 1; else hi = mid; }
    int first = lo;
    lo = 0; hi = NL;
    while (lo < hi) { int mid = (lo + hi) >> 1; if (batch[mid] < g + 1) lo = mid + 1; else hi = mid; }
    cnt[g] = (float)(lo - first);
}

__global__ void pool_final(const float* __restrict__ sums, const float* __restrict__ cnt,
                           float* __restrict__ out) {
    int idx = blockIdx.x * blockDim.x + threadIdx.x;   // NG*H
    int g = idx / H;
    out[idx] = sums[idx] / fmaxf(cnt[g], 1.f);
}

static inline size_t rup(size_t n) { return (n + 15) & ~(size_t)15; }   // 16-elem align

extern "C" void kernel_launch(void* const* d_in, const int* in_sizes, int n_in,
                              void* d_out, int out_size, void* d_ws, size_t ws_size,
                              hipStream_t stream) {
    const float* x_node = (const float*)d_in[0];
    const float* x_link = (const float*)d_in[1];
    const float* Wm_nl  = (const float*)d_in[2];
    const float* bm_nl  = (const float*)d_in[3];
    const float* Wu_nl  = (const float*)d_in[4];
    const float* bu_nl  = (const float*)d_in[5];
    const float* Wm_ln  = (const float*)d_in[6];
    const float* bm_ln  = (const float*)d_in[7];
    const float* Wu_ln  = (const float*)d_in[8];
    const float* bu_ln  = (const float*)d_in[9];
    const int* nl_edge  = (const int*)d_in[10];
    const int* ln_edge  = (const int*)d_in[11];
    const int* batch_link = (const int*)d_in[12];

    // workspace layout (4-byte elements), ~108 MB total
    char* wsb = (char*)d_ws;
    size_t o = 0;
    auto alloc = [&](size_t elems) { void* p = wsb + o * 4; o += rup(elems); return p; };
    float* xn    = (float*)alloc((size_t)NN * H);
    float* xl    = (float*)alloc((size_t)NL * H);
    float* Sl    = (float*)alloc((size_t)NL * H);
    float* Sn    = (float*)alloc((size_t)NN * H);
    float* deg_l = (float*)alloc(NL);
    float* deg_n = (float*)alloc(NN);
    int*   idl   = (int*)alloc(NL);        // int degree (contig with idn for memset)
    int*   idn   = (int*)alloc(NN);
    int*   offL  = (int*)alloc(NL + 1);
    int*   offN  = (int*)alloc(NN + 1);
    int*   curL  = (int*)alloc(NL);
    int*   curN  = (int*)alloc(NN);
    int*   adjL  = (int*)alloc(NE);
    int*   adjN  = (int*)alloc(NE);
    float* Wstack= (float*)alloc(4L * 384 * H);
    float* bmp   = (float*)alloc(4 * H);
    float* sums  = (float*)alloc(NG * H);
    float* cnt   = (float*)alloc(NG);
    (void)ws_size; (void)cnt;

    // zero int degrees + pool sums
    hipMemsetAsync(idl, 0, (size_t)(rup(NL) + NN) * sizeof(int), stream);
    hipMemsetAsync(sums, 0, (size_t)NG * H * sizeof(float), stream);

    precompute_w<<<(4 * (384 * H + H) + 255) / 256, 256, 0, stream>>>(
        Wm_nl, bm_nl, Wu_nl, Wm_ln, bm_ln, Wu_ln, Wstack, bmp);
    init_x<<<(2 * NN * H) / 256, 256, 0, stream>>>(x_node, x_link, xn, xl);
    compute_deg<<<(NE + 255) / 256, 256, 0, stream>>>(nl_edge, ln_edge, idl, idn);
    build_offsets<<<2, 256, 0, stream>>>(idl, idn, offL, offN, curL, curN, deg_l, deg_n);
    fill_csr<<<(NE + 255) / 256, 256, 0, stream>>>(nl_edge, ln_edge, curL, curN, adjL, adjN);
    pool_counts<<<1, 64, 0, stream>>>(batch_link, cnt);

    const float* bu_nl_l[2] = { bu_nl, bu_nl + H };
    const float* bu_ln_l[2] = { bu_ln, bu_ln + H };

    for (int l = 0; l < 2; ++l) {
        // aggregate raw features via CSR gather (reads OLD xn/xl)
        gather_sum<<<(NL + 3) / 4, 256, 0, stream>>>(offL, adjL, xn, Sl, NL);
        gather_sum<<<(NN + 3) / 4, 256, 0, stream>>>(offN, adjN, xl, Sn, NN);
        // fused message+update GEMMs (in-place row-wise updates)
        gemm_update<<<(NL + BM - 1) / BM, 256, 0, stream>>>(
            Sl, xl, deg_l, Wstack + (size_t)(2 * l) * 384 * H, bmp + (2 * l) * H,
            bu_nl_l[l], xl, NL);
        gemm_update<<<(NN + BM - 1) / BM, 256, 0, stream>>>(
            Sn, xn, deg_n, Wstack + (size_t)(2 * l + 1) * 384 * H, bmp + (2 * l + 1) * H,
            bu_ln_l[l], xn, NN);
    }

    pool_sum<<<(NL + PR - 1) / PR, 256, 0, stream>>>(xl, batch_link, sums);
    pool_final<<<(NG * H) / 256, 256, 0, stream>>>(sums, cnt, (float*)d_out);
}

// Round 3
// 469.374 us; speedup vs baseline: 7.4110x; 1.6415x over previous
//
#include <hip/hip_runtime.h>

// HeteroGNN fused implementation, round 3.
// Algebra: new = relu( S @ (Wm_top@Wu_top) + deg.*(x @ (Wm_bot@Wu_top)) + x @ Wu_bot
//                      + deg.*(bm@Wu_top) + bu )
// Round-3 changes:
//  - build_offsets (171us serial 2-block scan) -> 3-phase parallel scan (<10us)
//  - layer-1 sparsity: raw features have only 8 nonzero cols -> 32B-row gather,
//    K=24 GEMM, init_x deleted (layer-1 GEMM writes full xn/xl directly)

#define H 128
#define NN 50000
#define NL 50000
#define NE 400000
#define NG 64
#define FR 8          // raw feature dim
#define SNB 49        // scan blocks per array: ceil(50000/1024)

// ---------------- weight fusion ----------------
__global__ void precompute_w(const float* __restrict__ Wm_nl, const float* __restrict__ bm_nl,
                             const float* __restrict__ Wu_nl,
                             const float* __restrict__ Wm_ln, const float* __restrict__ bm_ln,
                             const float* __restrict__ Wu_ln,
                             float* __restrict__ Wstack, float* __restrict__ bmp) {
    int idx = blockIdx.x * blockDim.x + threadIdx.x;
    const int per = 384 * H + H;
    int c = idx / per, r = idx % per;
    if (c >= 4) return;
    int l = c >> 1, rel = c & 1;
    const float* Wm = (rel ? Wm_ln : Wm_nl) + l * 256 * H;
    const float* Wu = (rel ? Wu_ln : Wu_nl) + l * 256 * H;
    const float* bm = (rel ? bm_ln : bm_nl) + l * H;
    float* Ws = Wstack + c * 384 * H;
    if (r < 384 * H) {
        int t = r / H, j = r % H;
        if (t < 256) {
            float acc = 0.f;
            for (int k = 0; k < H; ++k) acc += Wm[t * H + k] * Wu[k * H + j];
            Ws[t * H + j] = acc;
        } else {
            Ws[t * H + j] = Wu[(t - 128) * H + j];
        }
    } else {
        int j = r - 384 * H;
        float acc = 0.f;
        for (int k = 0; k < H; ++k) acc += bm[k] * Wu[k * H + j];
        bmp[c * H + j] = acc;
    }
}

// ---------------- degree (int) ----------------
__global__ void compute_deg(const int* __restrict__ nl, const int* __restrict__ ln,
                            int* __restrict__ dl, int* __restrict__ dn) {
    int e = blockIdx.x * blockDim.x + threadIdx.x;
    if (e < NE) {
        atomicAdd(&dl[nl[NE + e]], 1);
        atomicAdd(&dn[ln[NE + e]], 1);
    }
}

// ---------------- 3-phase parallel scan over degrees ----------------
// phase 1: per-block (1024 elems) sums. blocks 0..SNB-1 -> L, SNB..2*SNB-1 -> N
__global__ void scan1(const int* __restrict__ degL, const int* __restrict__ degN,
                      int* __restrict__ bsum) {
    int arr = blockIdx.x / SNB, blk = blockIdx.x % SNB;
    const int* deg = arr ? degN : degL;
    int tid = threadIdx.x;
    int base = blk * 1024 + tid * 4;
    int s = 0;
#pragma unroll
    for (int i = 0; i < 4; ++i) { int idx = base + i; if (idx < NL) s += deg[idx]; }
    __shared__ int red[256];
    red[tid] = s;
    __syncthreads();
    for (int d = 128; d > 0; d >>= 1) {
        if (tid < d) red[tid] += red[tid + d];
        __syncthreads();
    }
    if (tid == 0) bsum[blockIdx.x] = red[0];
}

// phase 2: single block exclusive-scans the 2*SNB block sums (independent per 49-group)
__global__ void scan2(const int* __restrict__ bsum, int* __restrict__ bbase) {
    __shared__ int sh[128];
    int tid = threadIdx.x;
    int v0 = (tid < 2 * SNB) ? bsum[tid] : 0;
    sh[tid] = v0;
    __syncthreads();
    int gstart = (tid < SNB) ? 0 : SNB;
    for (int d = 1; d < 64; d <<= 1) {
        int v = (tid >= gstart + d && tid < 2 * SNB) ? sh[tid - d] : 0;
        __syncthreads();
        sh[tid] += v;
        __syncthreads();
    }
    if (tid < 2 * SNB) bbase[tid] = sh[tid] - v0;   // exclusive
}

// phase 3: per-block scan + write off/cur/fdeg
__global__ void scan3(const int* __restrict__ degL, const int* __restrict__ degN,
                      const int* __restrict__ bbase,
                      int* __restrict__ offL, int* __restrict__ offN,
                      int* __restrict__ curL, int* __restrict__ curN,
                      float* __restrict__ fdegL, float* __restrict__ fdegN) {
    int arr = blockIdx.x / SNB, blk = blockIdx.x % SNB;
    const int* deg = arr ? degN : degL;
    int* off = arr ? offN : offL;
    int* cur = arr ? curN : curL;
    float* fdeg = arr ? fdegN : fdegL;
    int tid = threadIdx.x;
    int base = blk * 1024 + tid * 4;
    int d4[4]; int s = 0;
#pragma unroll
    for (int i = 0; i < 4; ++i) {
        int idx = base + i;
        d4[i] = (idx < NL) ? deg[idx] : 0;
        s += d4[i];
    }
    __shared__ int part[256];
    part[tid] = s;
    __syncthreads();
    for (int d = 1; d < 256; d <<= 1) {
        int v = (tid >= d) ? part[tid - d] : 0;
        __syncthreads();
        part[tid] += v;
        __syncthreads();
    }
    int run = bbase[blockIdx.x] + part[tid] - s;   // exclusive prefix
#pragma unroll
    for (int i = 0; i < 4; ++i) {
        int idx = base + i;
        if (idx < NL) {
            off[idx] = run; cur[idx] = run; fdeg[idx] = (float)d4[i];
            run += d4[i];
            if (idx == NL - 1) off[NL] = run;
        }
    }
}

// ---------------- CSR fill ----------------
__global__ void fill_csr(const int* __restrict__ nl, const int* __restrict__ ln,
                         int* __restrict__ curL, int* __restrict__ curN,
                         int* __restrict__ adjL, int* __restrict__ adjN) {
    int e = blockIdx.x * blockDim.x + threadIdx.x;
    if (e >= NE) return;
    {
        int src = nl[e], dst = nl[NE + e];
        int p = atomicAdd(&curL[dst], 1);
        adjL[p] = src;
    }
    {
        int src = ln[e], dst = ln[NE + e];
        int p = atomicAdd(&curN[dst], 1);
        adjN[p] = src;
    }
}

// ---------------- layer-1 gather: raw 8-col rows ----------------
__launch_bounds__(256)
__global__ void gather_sum8(const int* __restrict__ off, const int* __restrict__ adj,
                            const float* __restrict__ Xraw, float* __restrict__ S8, int M) {
    int t = blockIdx.x * 256 + threadIdx.x;
    int row = t >> 3, c = t & 7;
    if (row >= M) return;
    int beg = off[row], end = off[row + 1];
    float acc = 0.f;
    for (int i = beg; i < end; ++i)
        acc += Xraw[(long)adj[i] * FR + c];
    S8[row * FR + c] = acc;
}

// ---------------- full gather-sum (layer 2) ----------------
__launch_bounds__(256)
__global__ void gather_sum(const int* __restrict__ off, const int* __restrict__ adj,
                           const float* __restrict__ X, float* __restrict__ S, int M) {
    int row = blockIdx.x * 4 + (threadIdx.x >> 6);
    int lane = threadIdx.x & 63;
    if (row >= M) return;
    int beg = off[row], end = off[row + 1];
    float2 acc = make_float2(0.f, 0.f);
    int i = beg;
    for (; i + 1 < end; i += 2) {
        int s0 = adj[i], s1 = adj[i + 1];
        float2 a = *(const float2*)(X + (long)s0 * H + lane * 2);
        float2 b = *(const float2*)(X + (long)s1 * H + lane * 2);
        acc.x += a.x + b.x;
        acc.y += a.y + b.y;
    }
    if (i < end) {
        float2 a = *(const float2*)(X + (long)adj[i] * H + lane * 2);
        acc.x += a.x;
        acc.y += a.y;
    }
    *(float2*)(S + (long)row * H + lane * 2) = acc;
}

// ---------------- fused update GEMM, layer 2 (K=384) ----------------
#define BM 64
#define BK 32
__launch_bounds__(256)
__global__ void gemm_update(const float* __restrict__ S, const float* __restrict__ X,
                            const float* __restrict__ deg, const float* __restrict__ Ws,
                            const float* __restrict__ bmp, const float* __restrict__ bu,
                            float* __restrict__ Out, int M) {
    __shared__ float At[BK][BM + 4];
    __shared__ float Bt[BK][H];
    int tid = threadIdx.x;
    int rowg = tid >> 4;
    int colg = tid & 15;
    int m0 = blockIdx.x * BM;
    float acc[4][8] = {};

    for (int k0 = 0; k0 < 384; k0 += BK) {
#pragma unroll
        for (int p = 0; p < 2; ++p) {
            int idx = tid + p * 256;
            int r = idx >> 3, kg = idx & 7;
            int row = m0 + r;
            int k = k0 + kg * 4;
            float4 v = make_float4(0.f, 0.f, 0.f, 0.f);
            if (row < M) {
                if (k < 128) {
                    v = *(const float4*)(S + (long)row * H + k);
                } else if (k < 256) {
                    v = *(const float4*)(X + (long)row * H + (k - 128));
                    float d = deg[row];
                    v.x *= d; v.y *= d; v.z *= d; v.w *= d;
                } else {
                    v = *(const float4*)(X + (long)row * H + (k - 256));
                }
            }
            At[kg * 4 + 0][r] = v.x;
            At[kg * 4 + 1][r] = v.y;
            At[kg * 4 + 2][r] = v.z;
            At[kg * 4 + 3][r] = v.w;
        }
#pragma unroll
        for (int p = 0; p < 4; ++p) {
            int idx = tid + p * 256;
            int kk = idx >> 5, c4 = idx & 31;
            *(float4*)(&Bt[kk][c4 * 4]) = *(const float4*)(Ws + (long)(k0 + kk) * H + c4 * 4);
        }
        __syncthreads();
#pragma unroll
        for (int kk = 0; kk < BK; ++kk) {
            float a[4], b[8];
            *(float4*)a = *(const float4*)(&At[kk][rowg * 4]);
            *(float4*)(b) = *(const float4*)(&Bt[kk][colg * 8]);
            *(float4*)(b + 4) = *(const float4*)(&Bt[kk][colg * 8 + 4]);
#pragma unroll
            for (int i = 0; i < 4; ++i)
#pragma unroll
                for (int j = 0; j < 8; ++j)
                    acc[i][j] += a[i] * b[j];
        }
        __syncthreads();
    }

    int colbase = colg * 8;
    float bmv[8], buv[8];
#pragma unroll
    for (int j = 0; j < 8; ++j) { bmv[j] = bmp[colbase + j]; buv[j] = bu[colbase + j]; }
#pragma unroll
    for (int i = 0; i < 4; ++i) {
        int row = m0 + rowg * 4 + i;
        if (row < M) {
            float d = deg[row];
            float o[8];
#pragma unroll
            for (int j = 0; j < 8; ++j) {
                float v = acc[i][j] + d * bmv[j] + buv[j];
                o[j] = v > 0.f ? v : 0.f;
            }
            *(float4*)(Out + (long)row * H + colbase) = *(float4*)o;
            *(float4*)(Out + (long)row * H + colbase + 4) = *(float4*)(o + 4);
        }
    }
}

// ---------------- fused update GEMM, layer 1 (K=24: cols 0..7 of S8, deg*Xraw, Xraw) ----------------
// Uses rows {0..7, 128..135, 256..263} of the full 384-row fused weight.
__launch_bounds__(256)
__global__ void gemm_update_l1(const float* __restrict__ S8, const float* __restrict__ Xraw,
                               const float* __restrict__ deg, const float* __restrict__ Ws,
                               const float* __restrict__ bmp, const float* __restrict__ bu,
                               float* __restrict__ Out, int M) {
    __shared__ float At[24][BM + 4];
    __shared__ float Bt[24][H];
    int tid = threadIdx.x;
    int rowg = tid >> 4;
    int colg = tid & 15;
    int m0 = blockIdx.x * BM;

    // stage A: 64 rows x 24 k  (1536 elems, 6 per thread)
#pragma unroll
    for (int p = 0; p < 6; ++p) {
        int lin = tid + p * 256;
        int r = lin / 24, k = lin % 24;
        int row = m0 + r;
        float v = 0.f;
        if (row < M) {
            if (k < 8)       v = S8[row * FR + k];
            else if (k < 16) v = deg[row] * Xraw[(long)row * FR + (k - 8)];
            else             v = Xraw[(long)row * FR + (k - 16)];
        }
        At[k][r] = v;
    }
    // stage B: 24 rows x 128 cols (3072 elems, 12 per thread)
#pragma unroll
    for (int p = 0; p < 12; ++p) {
        int lin = tid + p * 256;
        int kk = lin >> 7, c = lin & 127;
        int srcrow = (kk >> 3) * 128 + (kk & 7);
        Bt[kk][c] = Ws[srcrow * H + c];
    }
    __syncthreads();

    float acc[4][8] = {};
#pragma unroll
    for (int kk = 0; kk < 24; ++kk) {
        float a[4], b[8];
        *(float4*)a = *(const float4*)(&At[kk][rowg * 4]);
        *(float4*)(b) = *(const float4*)(&Bt[kk][colg * 8]);
        *(float4*)(b + 4) = *(const float4*)(&Bt[kk][colg * 8 + 4]);
#pragma unroll
        for (int i = 0; i < 4; ++i)
#pragma unroll
            for (int j = 0; j < 8; ++j)
                acc[i][j] += a[i] * b[j];
    }

    int colbase = colg * 8;
    float bmv[8], buv[8];
#pragma unroll
    for (int j = 0; j < 8; ++j) { bmv[j] = bmp[colbase + j]; buv[j] = bu[colbase + j]; }
#pragma unroll
    for (int i = 0; i < 4; ++i) {
        int row = m0 + rowg * 4 + i;
        if (row < M) {
            float d = deg[row];
            float o[8];
#pragma unroll
            for (int j = 0; j < 8; ++j) {
                float v = acc[i][j] + d * bmv[j] + buv[j];
                o[j] = v > 0.f ? v : 0.f;
            }
            *(float4*)(Out + (long)row * H + colbase) = *(float4*)o;
            *(float4*)(Out + (long)row * H + colbase + 4) = *(float4*)(o + 4);
        }
    }
}

// ---------------- global mean pool ----------------
#define PR 256
__global__ void pool_sum(const float* __restrict__ xl, const int* __restrict__ batch,
                         float* __restrict__ sums) {
    int base = blockIdx.x * PR;
    int col = threadIdx.x & 127;
    int half = threadIdx.x >> 7;
    int rows = min(PR, NL - base);
    float acc = 0.f;
    int cur = -1;
    for (int r = half; r < rows; r += 2) {
        int row = base + r;
        int g = batch[row];
        if (g != cur) {
            if (cur >= 0) atomicAdd(&sums[cur * H + col], acc);
            acc = 0.f;
            cur = g;
        }
        acc += xl[(long)row * H + col];
    }
    if (cur >= 0) atomicAdd(&sums[cur * H + col], acc);
}

__global__ void pool_counts(const int* __restrict__ batch, float* __restrict__ cnt) {
    int g = threadIdx.x;
    if (g >= NG) return;
    int lo = 0, hi = NL;
    while (lo < hi) { int mid = (lo + hi) >> 1; if (batch[mid] < g) lo = mid + 1; else hi = mid; }
    int first = lo;
    lo = 0; hi = NL;
    while (lo < hi) { int mid = (lo + hi) >> 1; if (batch[mid] < g + 1) lo = mid + 1; else hi = mid; }
    cnt[g] = (float)(lo - first);
}

__global__ void pool_final(const float* __restrict__ sums, const float* __restrict__ cnt,
                           float* __restrict__ out) {
    int idx = blockIdx.x * blockDim.x + threadIdx.x;
    int g = idx / H;
    out[idx] = sums[idx] / fmaxf(cnt[g], 1.f);
}

static inline size_t rup(size_t n) { return (n + 15) & ~(size_t)15; }

extern "C" void kernel_launch(void* const* d_in, const int* in_sizes, int n_in,
                              void* d_out, int out_size, void* d_ws, size_t ws_size,
                              hipStream_t stream) {
    const float* x_node = (const float*)d_in[0];
    const float* x_link = (const float*)d_in[1];
    const float* Wm_nl  = (const float*)d_in[2];
    const float* bm_nl  = (const float*)d_in[3];
    const float* Wu_nl  = (const float*)d_in[4];
    const float* bu_nl  = (const float*)d_in[5];
    const float* Wm_ln  = (const float*)d_in[6];
    const float* bm_ln  = (const float*)d_in[7];
    const float* Wu_ln  = (const float*)d_in[8];
    const float* bu_ln  = (const float*)d_in[9];
    const int* nl_edge  = (const int*)d_in[10];
    const int* ln_edge  = (const int*)d_in[11];
    const int* batch_link = (const int*)d_in[12];

    char* wsb = (char*)d_ws;
    size_t o = 0;
    auto alloc = [&](size_t elems) { void* p = wsb + o * 4; o += rup(elems); return p; };
    float* xn    = (float*)alloc((size_t)NN * H);
    float* xl    = (float*)alloc((size_t)NL * H);
    float* Sl    = (float*)alloc((size_t)NL * H);   // doubles as S8L (layer 1)
    float* Sn    = (float*)alloc((size_t)NN * H);   // doubles as S8N (layer 1)
    float* deg_l = (float*)alloc(NL);
    float* deg_n = (float*)alloc(NN);
    int*   idl   = (int*)alloc(NL);
    int*   idn   = (int*)alloc(NN);
    int*   offL  = (int*)alloc(NL + 1);
    int*   offN  = (int*)alloc(NN + 1);
    int*   curL  = (int*)alloc(NL);
    int*   curN  = (int*)alloc(NN);
    int*   adjL  = (int*)alloc(NE);
    int*   adjN  = (int*)alloc(NE);
    float* Wstack= (float*)alloc(4L * 384 * H);
    float* bmp   = (float*)alloc(4 * H);
    float* sums  = (float*)alloc(NG * H);
    float* cnt   = (float*)alloc(NG);
    int*   bsum  = (int*)alloc(2 * SNB);
    int*   bbase = (int*)alloc(2 * SNB);
    (void)ws_size;

    hipMemsetAsync(idl, 0, (size_t)(rup(NL) + NN) * sizeof(int), stream);
    hipMemsetAsync(sums, 0, (size_t)NG * H * sizeof(float), stream);

    precompute_w<<<(4 * (384 * H + H) + 255) / 256, 256, 0, stream>>>(
        Wm_nl, bm_nl, Wu_nl, Wm_ln, bm_ln, Wu_ln, Wstack, bmp);
    compute_deg<<<(NE + 255) / 256, 256, 0, stream>>>(nl_edge, ln_edge, idl, idn);
    scan1<<<2 * SNB, 256, 0, stream>>>(idl, idn, bsum);
    scan2<<<1, 128, 0, stream>>>(bsum, bbase);
    scan3<<<2 * SNB, 256, 0, stream>>>(idl, idn, bbase, offL, offN, curL, curN, deg_l, deg_n);
    fill_csr<<<(NE + 255) / 256, 256, 0, stream>>>(nl_edge, ln_edge, curL, curN, adjL, adjN);
    pool_counts<<<1, 64, 0, stream>>>(batch_link, cnt);

    // ---- layer 1 (raw 8-col inputs) ----
    gather_sum8<<<(NL * FR + 255) / 256, 256, 0, stream>>>(offL, adjL, x_node, Sl, NL);
    gather_sum8<<<(NN * FR + 255) / 256, 256, 0, stream>>>(offN, adjN, x_link, Sn, NN);
    gemm_update_l1<<<(NL + BM - 1) / BM, 256, 0, stream>>>(
        Sl, x_link, deg_l, Wstack + 0 * 384 * H, bmp + 0 * H, bu_nl, xl, NL);
    gemm_update_l1<<<(NN + BM - 1) / BM, 256, 0, stream>>>(
        Sn, x_node, deg_n, Wstack + 1 * 384 * H, bmp + 1 * H, bu_ln, xn, NN);

    // ---- layer 2 (full 128-col) ----
    gather_sum<<<(NL + 3) / 4, 256, 0, stream>>>(offL, adjL, xn, Sl, NL);
    gather_sum<<<(NN + 3) / 4, 256, 0, stream>>>(offN, adjN, xl, Sn, NN);
    gemm_update<<<(NL + BM - 1) / BM, 256, 0, stream>>>(
        Sl, xl, deg_l, Wstack + (size_t)2 * 384 * H, bmp + 2 * H, bu_nl + H, xl, NL);
    gemm_update<<<(NN + BM - 1) / BM, 256, 0, stream>>>(
        Sn, xn, deg_n, Wstack + (size_t)3 * 384 * H, bmp + 3 * H, bu_ln + H, xn, NN);

    pool_sum<<<(NL + PR - 1) / PR, 256, 0, stream>>>(xl, batch_link, sums);
    pool_final<<<(NG * H) / 256, 256, 0, stream>>>(sums, cnt, (float*)d_out);
}